// Round 1
// baseline (1484.211 us; speedup 1.0000x reference)
//
#include <hip/hip_runtime.h>
#include <math.h>

#define NNODES 50000
#define NF     128
#define NEDGES 800000

// ---------------------------------------------------------------------------
// Kernel 1: S = alpha * h0   (S lives in d_out; overwrites the 0xAA poison)
// ---------------------------------------------------------------------------
__global__ __launch_bounds__(256) void init_support(const float* __restrict__ h0,
                                                    const float* __restrict__ alpha_p,
                                                    float* __restrict__ S) {
    const float alpha = alpha_p[0];
    int i = (blockIdx.x * 256 + threadIdx.x) * 4;
    if (i < NNODES * NF) {
        float4 h = *(const float4*)(h0 + i);
        float4 v;
        v.x = alpha * h.x; v.y = alpha * h.y; v.z = alpha * h.z; v.w = alpha * h.w;
        *(float4*)(S + i) = v;
    }
}

// ---------------------------------------------------------------------------
// Kernel 2: S[dst] += (1-alpha) * edge_w[e] * x[src]   (32 lanes per edge,
// float4 per lane, native fp32 global atomics)
// ---------------------------------------------------------------------------
__global__ __launch_bounds__(256) void scatter_edges(const float* __restrict__ x,
                                                     const float* __restrict__ ew,
                                                     const int* __restrict__ src,
                                                     const int* __restrict__ dst,
                                                     const float* __restrict__ alpha_p,
                                                     float* __restrict__ S) {
    int gid  = blockIdx.x * 256 + threadIdx.x;
    int e    = gid >> 5;
    int lane = gid & 31;
    if (e >= NEDGES) return;
    const float coef = (1.0f - alpha_p[0]) * ew[e];
    const int s = src[e];
    const int d = dst[e];
    const float4 xs = *(const float4*)(x + (long)s * NF + lane * 4);
    float* outp = S + (long)d * NF + lane * 4;
    unsafeAtomicAdd(outp + 0, coef * xs.x);
    unsafeAtomicAdd(outp + 1, coef * xs.y);
    unsafeAtomicAdd(outp + 2, coef * xs.z);
    unsafeAtomicAdd(outp + 3, coef * xs.w);
}

// ---------------------------------------------------------------------------
// Kernel 3: out = theta*(S@W) + (1-theta)*S + x, in place over S (=d_out).
// Each block owns 32 rows: stages them (transposed) + full W into LDS, then
// overwrites those same rows. Row-local => in-place is safe.
// Thread mapping: cg = tid&31 -> 4 cols, slot = tid>>5 -> 4 rows.
// Per k-step: 2x ds_read_b128 + 16 v_fma (FMA-bound).
// LDS: 64KB (W) + 16KB (sT) = 80KB -> 2 blocks/CU on gfx950's 160KB.
// ---------------------------------------------------------------------------
__global__ __launch_bounds__(256) void gemm_out(float* __restrict__ S,
                                                const float* __restrict__ W,
                                                const float* __restrict__ x,
                                                const float* __restrict__ lamda_p,
                                                const int* __restrict__ l_p) {
    __shared__ float Wl[NF * NF];   // W[k][j], 64 KB
    __shared__ float sT[NF * 32];   // sT[k][r_local], 16 KB

    const int tid = threadIdx.x;
    const int rbase = blockIdx.x * 32;

    // stage W: 4096 float4s over 256 threads
    {
        const float4* Wv = (const float4*)W;
        float4* Wlv = (float4*)Wl;
        #pragma unroll
        for (int i = 0; i < 16; i++)
            Wlv[tid + i * 256] = Wv[tid + i * 256];
    }
    // stage 32 rows of S, transposed
    {
        int rl = tid >> 3;               // 0..31
        int c0 = (tid & 7) * 16;         // 0,16,...,112
        int row = rbase + rl;
        #pragma unroll
        for (int cc = 0; cc < 16; cc += 4) {
            int c = c0 + cc;
            float4 v = (row < NNODES) ? *(const float4*)(S + (long)row * NF + c)
                                      : make_float4(0.f, 0.f, 0.f, 0.f);
            sT[(c + 0) * 32 + rl] = v.x;
            sT[(c + 1) * 32 + rl] = v.y;
            sT[(c + 2) * 32 + rl] = v.z;
            sT[(c + 3) * 32 + rl] = v.w;
        }
    }
    __syncthreads();

    const int cg   = tid & 31;
    const int slot = tid >> 5;
    const int j0   = cg * 4;
    const int rl0  = slot * 4;

    float acc[4][4];
    #pragma unroll
    for (int r = 0; r < 4; r++)
        #pragma unroll
        for (int c = 0; c < 4; c++) acc[r][c] = 0.f;

    #pragma unroll 4
    for (int k = 0; k < NF; k++) {
        float4 w = *(const float4*)&Wl[k * NF + j0];
        float4 s = *(const float4*)&sT[k * 32 + rl0];
        acc[0][0] += s.x * w.x; acc[0][1] += s.x * w.y; acc[0][2] += s.x * w.z; acc[0][3] += s.x * w.w;
        acc[1][0] += s.y * w.x; acc[1][1] += s.y * w.y; acc[1][2] += s.y * w.z; acc[1][3] += s.y * w.w;
        acc[2][0] += s.z * w.x; acc[2][1] += s.z * w.y; acc[2][2] += s.z * w.z; acc[2][3] += s.z * w.w;
        acc[3][0] += s.w * w.x; acc[3][1] += s.w * w.y; acc[3][2] += s.w * w.z; acc[3][3] += s.w * w.w;
    }

    const float theta = logf(lamda_p[0] / (float)l_p[0] + 1.0f);
    const float omt   = 1.0f - theta;

    #pragma unroll
    for (int r = 0; r < 4; r++) {
        int row = rbase + rl0 + r;
        if (row < NNODES) {
            float4 xv = *(const float4*)(x + (long)row * NF + j0);
            float4 o;
            o.x = theta * acc[r][0] + omt * sT[(j0 + 0) * 32 + rl0 + r] + xv.x;
            o.y = theta * acc[r][1] + omt * sT[(j0 + 1) * 32 + rl0 + r] + xv.y;
            o.z = theta * acc[r][2] + omt * sT[(j0 + 2) * 32 + rl0 + r] + xv.z;
            o.w = theta * acc[r][3] + omt * sT[(j0 + 3) * 32 + rl0 + r] + xv.w;
            *(float4*)(S + (long)row * NF + j0) = o;
        }
    }
}

// ---------------------------------------------------------------------------
extern "C" void kernel_launch(void* const* d_in, const int* in_sizes, int n_in,
                              void* d_out, int out_size, void* d_ws, size_t ws_size,
                              hipStream_t stream) {
    const float* x       = (const float*)d_in[0];
    const float* h0      = (const float*)d_in[1];
    const float* edge_w  = (const float*)d_in[2];
    const float* weight  = (const float*)d_in[3];
    const float* lamda   = (const float*)d_in[4];
    const float* alpha   = (const float*)d_in[5];
    const int*   src     = (const int*)d_in[6];
    const int*   dst     = (const int*)d_in[7];
    const int*   l       = (const int*)d_in[8];
    float* out = (float*)d_out;

    // 1) S = alpha*h0  (S aliases d_out)
    init_support<<<(NNODES * NF / 4 + 255) / 256, 256, 0, stream>>>(h0, alpha, out);
    // 2) S[dst] += (1-alpha)*w_e*x[src]
    scatter_edges<<<(NEDGES * 32 + 255) / 256, 256, 0, stream>>>(x, edge_w, src, dst, alpha, out);
    // 3) out = theta*(S@W) + (1-theta)*S + x  (in place, row-local)
    gemm_out<<<(NNODES + 31) / 32, 256, 0, stream>>>(out, weight, x, lamda, l);
}

// Round 2
// 418.137 us; speedup vs baseline: 3.5496x; 3.5496x over previous
//
#include <hip/hip_runtime.h>
#include <math.h>

#define NNODES 50000
#define NF     128
#define NEDGES 800000

// ============================ CSR build =====================================

// deg[dst]++ per edge (int atomics, heavily same-address-coalesced)
__global__ __launch_bounds__(256) void hist_kernel(const int* __restrict__ dst,
                                                   int* __restrict__ deg) {
    int e = blockIdx.x * 256 + threadIdx.x;
    if (e < NEDGES) atomicAdd(&deg[dst[e]], 1);
}

// Single-block exclusive scan: 256 threads, each serially scans a contiguous
// chunk of ceil(N/256) entries; block-scan of the 256 partials in LDS.
// Writes offsets[0..N] and a working copy cursor[0..N-1].
__global__ __launch_bounds__(256) void scan_kernel(const int* __restrict__ deg,
                                                   int* __restrict__ offs,
                                                   int* __restrict__ cursor) {
    __shared__ int part[256];
    const int tid = threadIdx.x;
    const int CH = (NNODES + 255) / 256;   // 196
    const int beg = tid * CH;
    const int end = min(beg + CH, NNODES);

    int s = 0;
    for (int i = beg; i < end; i++) s += deg[i];
    part[tid] = s;
    __syncthreads();
    // Hillis-Steele inclusive scan on part[]
    for (int off = 1; off < 256; off <<= 1) {
        int v = (tid >= off) ? part[tid - off] : 0;
        __syncthreads();
        part[tid] += v;
        __syncthreads();
    }
    int running = (tid == 0) ? 0 : part[tid - 1];   // exclusive base
    for (int i = beg; i < end; i++) {
        offs[i] = running;
        cursor[i] = running;
        running += deg[i];
    }
    if (tid == 0) offs[NNODES] = NEDGES;
}

// csr fill: pos = cursor[dst]++; store src and pre-scaled coefficient
__global__ __launch_bounds__(256) void fill_kernel(const int* __restrict__ src,
                                                   const int* __restrict__ dst,
                                                   const float* __restrict__ ew,
                                                   const float* __restrict__ alpha_p,
                                                   int* __restrict__ cursor,
                                                   int* __restrict__ csr_src,
                                                   float* __restrict__ csr_w) {
    int e = blockIdx.x * 256 + threadIdx.x;
    if (e >= NEDGES) return;
    int d = dst[e];
    int pos = atomicAdd(&cursor[d], 1);
    csr_src[pos] = src[e];
    csr_w[pos] = (1.0f - alpha_p[0]) * ew[e];
}

// ======================= pull-phase SpMM ====================================
// 32 lanes per dst node (lane owns float4 feature chunk); 8 nodes per block.
// S[node] = alpha*h0[node] + sum_e coef_e * x[src_e]   (non-atomic write)
__global__ __launch_bounds__(256) void pull_kernel(const float* __restrict__ x,
                                                   const float* __restrict__ h0,
                                                   const float* __restrict__ alpha_p,
                                                   const int* __restrict__ offs,
                                                   const int* __restrict__ csr_src,
                                                   const float* __restrict__ csr_w,
                                                   float* __restrict__ S) {
    const int tid = threadIdx.x;
    const int node = blockIdx.x * 8 + (tid >> 5);
    if (node >= NNODES) return;
    const int j0 = (tid & 31) * 4;
    const float alpha = alpha_p[0];

    const float4 h = *(const float4*)(h0 + (long)node * NF + j0);
    float4 acc;
    acc.x = alpha * h.x; acc.y = alpha * h.y; acc.z = alpha * h.z; acc.w = alpha * h.w;

    const int beg = offs[node];
    const int end = offs[node + 1];
    for (int i = beg; i < end; i++) {
        const int s = csr_src[i];
        const float w = csr_w[i];
        const float4 xv = *(const float4*)(x + (long)s * NF + j0);
        acc.x += w * xv.x; acc.y += w * xv.y; acc.z += w * xv.z; acc.w += w * xv.w;
    }
    *(float4*)(S + (long)node * NF + j0) = acc;
}

// ===================== fallback (round-1 path) ==============================

__global__ __launch_bounds__(256) void init_support(const float* __restrict__ h0,
                                                    const float* __restrict__ alpha_p,
                                                    float* __restrict__ S) {
    const float alpha = alpha_p[0];
    int i = (blockIdx.x * 256 + threadIdx.x) * 4;
    if (i < NNODES * NF) {
        float4 h = *(const float4*)(h0 + i);
        float4 v;
        v.x = alpha * h.x; v.y = alpha * h.y; v.z = alpha * h.z; v.w = alpha * h.w;
        *(float4*)(S + i) = v;
    }
}

__global__ __launch_bounds__(256) void scatter_edges(const float* __restrict__ x,
                                                     const float* __restrict__ ew,
                                                     const int* __restrict__ src,
                                                     const int* __restrict__ dst,
                                                     const float* __restrict__ alpha_p,
                                                     float* __restrict__ S) {
    int gid  = blockIdx.x * 256 + threadIdx.x;
    int e    = gid >> 5;
    int lane = gid & 31;
    if (e >= NEDGES) return;
    const float coef = (1.0f - alpha_p[0]) * ew[e];
    const int s = src[e];
    const int d = dst[e];
    const float4 xs = *(const float4*)(x + (long)s * NF + lane * 4);
    float* outp = S + (long)d * NF + lane * 4;
    unsafeAtomicAdd(outp + 0, coef * xs.x);
    unsafeAtomicAdd(outp + 1, coef * xs.y);
    unsafeAtomicAdd(outp + 2, coef * xs.z);
    unsafeAtomicAdd(outp + 3, coef * xs.w);
}

// ========================= epilogue GEMM ====================================
// out = theta*(S@W) + (1-theta)*S + x, in place over S (=d_out). Row-local.
__global__ __launch_bounds__(256) void gemm_out(float* __restrict__ S,
                                                const float* __restrict__ W,
                                                const float* __restrict__ x,
                                                const float* __restrict__ lamda_p,
                                                const int* __restrict__ l_p) {
    __shared__ float Wl[NF * NF];   // 64 KB
    __shared__ float sT[NF * 32];   // 16 KB

    const int tid = threadIdx.x;
    const int rbase = blockIdx.x * 32;

    {
        const float4* Wv = (const float4*)W;
        float4* Wlv = (float4*)Wl;
        #pragma unroll
        for (int i = 0; i < 16; i++)
            Wlv[tid + i * 256] = Wv[tid + i * 256];
    }
    {
        int rl = tid >> 3;
        int c0 = (tid & 7) * 16;
        int row = rbase + rl;
        #pragma unroll
        for (int cc = 0; cc < 16; cc += 4) {
            int c = c0 + cc;
            float4 v = (row < NNODES) ? *(const float4*)(S + (long)row * NF + c)
                                      : make_float4(0.f, 0.f, 0.f, 0.f);
            sT[(c + 0) * 32 + rl] = v.x;
            sT[(c + 1) * 32 + rl] = v.y;
            sT[(c + 2) * 32 + rl] = v.z;
            sT[(c + 3) * 32 + rl] = v.w;
        }
    }
    __syncthreads();

    const int cg   = tid & 31;
    const int slot = tid >> 5;
    const int j0   = cg * 4;
    const int rl0  = slot * 4;

    float acc[4][4];
    #pragma unroll
    for (int r = 0; r < 4; r++)
        #pragma unroll
        for (int c = 0; c < 4; c++) acc[r][c] = 0.f;

    #pragma unroll 4
    for (int k = 0; k < NF; k++) {
        float4 w = *(const float4*)&Wl[k * NF + j0];
        float4 s = *(const float4*)&sT[k * 32 + rl0];
        acc[0][0] += s.x * w.x; acc[0][1] += s.x * w.y; acc[0][2] += s.x * w.z; acc[0][3] += s.x * w.w;
        acc[1][0] += s.y * w.x; acc[1][1] += s.y * w.y; acc[1][2] += s.y * w.z; acc[1][3] += s.y * w.w;
        acc[2][0] += s.z * w.x; acc[2][1] += s.z * w.y; acc[2][2] += s.z * w.z; acc[2][3] += s.z * w.w;
        acc[3][0] += s.w * w.x; acc[3][1] += s.w * w.y; acc[3][2] += s.w * w.z; acc[3][3] += s.w * w.w;
    }

    const float theta = logf(lamda_p[0] / (float)l_p[0] + 1.0f);
    const float omt   = 1.0f - theta;

    #pragma unroll
    for (int r = 0; r < 4; r++) {
        int row = rbase + rl0 + r;
        if (row < NNODES) {
            float4 xv = *(const float4*)(x + (long)row * NF + j0);
            float4 o;
            o.x = theta * acc[r][0] + omt * sT[(j0 + 0) * 32 + rl0 + r] + xv.x;
            o.y = theta * acc[r][1] + omt * sT[(j0 + 1) * 32 + rl0 + r] + xv.y;
            o.z = theta * acc[r][2] + omt * sT[(j0 + 2) * 32 + rl0 + r] + xv.z;
            o.w = theta * acc[r][3] + omt * sT[(j0 + 3) * 32 + rl0 + r] + xv.w;
            *(float4*)(S + (long)row * NF + j0) = o;
        }
    }
}

// ===========================================================================
extern "C" void kernel_launch(void* const* d_in, const int* in_sizes, int n_in,
                              void* d_out, int out_size, void* d_ws, size_t ws_size,
                              hipStream_t stream) {
    const float* x       = (const float*)d_in[0];
    const float* h0      = (const float*)d_in[1];
    const float* edge_w  = (const float*)d_in[2];
    const float* weight  = (const float*)d_in[3];
    const float* lamda   = (const float*)d_in[4];
    const float* alpha   = (const float*)d_in[5];
    const int*   src     = (const int*)d_in[6];
    const int*   dst     = (const int*)d_in[7];
    const int*   l       = (const int*)d_in[8];
    float* out = (float*)d_out;

    // workspace layout
    const size_t need = (size_t)(NNODES + (NNODES + 1) + NNODES + NEDGES + NEDGES) * 4;
    if (ws_size >= need) {
        int*   deg     = (int*)d_ws;
        int*   offs    = deg + NNODES;
        int*   cursor  = offs + NNODES + 1;
        int*   csr_src = cursor + NNODES;
        float* csr_w   = (float*)(csr_src + NEDGES);

        hipMemsetAsync(deg, 0, NNODES * sizeof(int), stream);
        hist_kernel<<<(NEDGES + 255) / 256, 256, 0, stream>>>(dst, deg);
        scan_kernel<<<1, 256, 0, stream>>>(deg, offs, cursor);
        fill_kernel<<<(NEDGES + 255) / 256, 256, 0, stream>>>(src, dst, edge_w, alpha,
                                                              cursor, csr_src, csr_w);
        pull_kernel<<<(NNODES + 7) / 8, 256, 0, stream>>>(x, h0, alpha, offs,
                                                          csr_src, csr_w, out);
    } else {
        // fallback: round-1 atomic scatter path
        init_support<<<(NNODES * NF / 4 + 255) / 256, 256, 0, stream>>>(h0, alpha, out);
        scatter_edges<<<(NEDGES * 32 + 255) / 256, 256, 0, stream>>>(x, edge_w, src, dst,
                                                                     alpha, out);
    }
    gemm_out<<<(NNODES + 31) / 32, 256, 0, stream>>>(out, weight, x, lamda, l);
}

// Round 3
// 302.720 us; speedup vs baseline: 4.9029x; 1.3813x over previous
//
#include <hip/hip_runtime.h>
#include <math.h>

#define NNODES 50000
#define NF     128
#define NEDGES 800000

#define SCAN_BLOCKS ((NNODES + 255) / 256)   // 196

// ============================ CSR build =====================================

// deg[dst]++ per edge (int atomics, heavily same-address-coalesced)
__global__ __launch_bounds__(256) void hist_kernel(const int* __restrict__ dst,
                                                   int* __restrict__ deg) {
    int e = blockIdx.x * 256 + threadIdx.x;
    if (e < NEDGES) atomicAdd(&deg[dst[e]], 1);
}

// S1: per-block 256-wide inclusive scan; store intra-block EXCLUSIVE prefix
// in place over deg[]; block total -> bsum[b].
__global__ __launch_bounds__(256) void scan1_kernel(int* __restrict__ deg,
                                                    int* __restrict__ bsum) {
    __shared__ int sc[256];
    const int t = threadIdx.x;
    const int i = blockIdx.x * 256 + t;
    const int v = (i < NNODES) ? deg[i] : 0;
    sc[t] = v;
    __syncthreads();
    #pragma unroll
    for (int off = 1; off < 256; off <<= 1) {
        int u = (t >= off) ? sc[t - off] : 0;
        __syncthreads();
        sc[t] += u;
        __syncthreads();
    }
    if (i < NNODES) deg[i] = sc[t] - v;          // exclusive within block
    if (t == 255) bsum[blockIdx.x] = sc[255];    // block total
}

// S2: scan the block sums -> exclusive block offsets boff[196]
__global__ __launch_bounds__(256) void scan2_kernel(const int* __restrict__ bsum,
                                                    int* __restrict__ boff) {
    __shared__ int sc[256];
    const int t = threadIdx.x;
    const int v = (t < SCAN_BLOCKS) ? bsum[t] : 0;
    sc[t] = v;
    __syncthreads();
    #pragma unroll
    for (int off = 1; off < 256; off <<= 1) {
        int u = (t >= off) ? sc[t - off] : 0;
        __syncthreads();
        sc[t] += u;
        __syncthreads();
    }
    if (t < SCAN_BLOCKS) boff[t] = sc[t] - v;    // exclusive
}

// S3: offs[i] = cursor[i] = deg[i] + boff[b]; offs[N] = E
__global__ __launch_bounds__(256) void scan3_kernel(const int* __restrict__ deg,
                                                    const int* __restrict__ boff,
                                                    int* __restrict__ offs,
                                                    int* __restrict__ cursor) {
    const int t = threadIdx.x;
    const int i = blockIdx.x * 256 + t;
    if (i < NNODES) {
        int o = deg[i] + boff[blockIdx.x];
        offs[i] = o;
        cursor[i] = o;
    }
    if (i == 0) offs[NNODES] = NEDGES;
}

// csr fill: pos = cursor[dst]++; store src and pre-scaled coefficient
__global__ __launch_bounds__(256) void fill_kernel(const int* __restrict__ src,
                                                   const int* __restrict__ dst,
                                                   const float* __restrict__ ew,
                                                   const float* __restrict__ alpha_p,
                                                   int* __restrict__ cursor,
                                                   int* __restrict__ csr_src,
                                                   float* __restrict__ csr_w) {
    int e = blockIdx.x * 256 + threadIdx.x;
    if (e >= NEDGES) return;
    int d = dst[e];
    int pos = atomicAdd(&cursor[d], 1);
    csr_src[pos] = src[e];
    csr_w[pos] = (1.0f - alpha_p[0]) * ew[e];
}

// ======================= pull-phase SpMM ====================================
// One 64-lane wave per node; the two 32-lane halves process even/odd edges
// (lane&31 owns a float4 feature chunk). Final cross-half __shfl_xor add.
// S[node] = alpha*h0[node] + sum_e coef_e * x[src_e]   (non-atomic write)
__global__ __launch_bounds__(256) void pull_kernel(const float* __restrict__ x,
                                                   const float* __restrict__ h0,
                                                   const float* __restrict__ alpha_p,
                                                   const int* __restrict__ offs,
                                                   const int* __restrict__ csr_src,
                                                   const float* __restrict__ csr_w,
                                                   float* __restrict__ S) {
    const int tid  = threadIdx.x;
    const int node = blockIdx.x * 4 + (tid >> 6);
    if (node >= NNODES) return;
    const int lane = tid & 63;
    const int eh   = lane >> 5;            // which edge of the pair
    const int j0   = (lane & 31) * 4;      // feature chunk

    const int beg = offs[node];
    const int end = offs[node + 1];

    float4 acc = make_float4(0.f, 0.f, 0.f, 0.f);
    for (int i = beg + eh; i < end; i += 2) {
        const int s   = csr_src[i];
        const float w = csr_w[i];
        const float4 xv = *(const float4*)(x + (long)s * NF + j0);
        acc.x += w * xv.x; acc.y += w * xv.y; acc.z += w * xv.z; acc.w += w * xv.w;
    }
    // combine the two halves (lane ^ 32)
    acc.x += __shfl_xor(acc.x, 32, 64);
    acc.y += __shfl_xor(acc.y, 32, 64);
    acc.z += __shfl_xor(acc.z, 32, 64);
    acc.w += __shfl_xor(acc.w, 32, 64);

    if (eh == 0) {
        const float alpha = alpha_p[0];
        const float4 h = *(const float4*)(h0 + (long)node * NF + j0);
        float4 o;
        o.x = alpha * h.x + acc.x;
        o.y = alpha * h.y + acc.y;
        o.z = alpha * h.z + acc.z;
        o.w = alpha * h.w + acc.w;
        *(float4*)(S + (long)node * NF + j0) = o;
    }
}

// ===================== fallback (round-1 path) ==============================

__global__ __launch_bounds__(256) void init_support(const float* __restrict__ h0,
                                                    const float* __restrict__ alpha_p,
                                                    float* __restrict__ S) {
    const float alpha = alpha_p[0];
    int i = (blockIdx.x * 256 + threadIdx.x) * 4;
    if (i < NNODES * NF) {
        float4 h = *(const float4*)(h0 + i);
        float4 v;
        v.x = alpha * h.x; v.y = alpha * h.y; v.z = alpha * h.z; v.w = alpha * h.w;
        *(float4*)(S + i) = v;
    }
}

__global__ __launch_bounds__(256) void scatter_edges(const float* __restrict__ x,
                                                     const float* __restrict__ ew,
                                                     const int* __restrict__ src,
                                                     const int* __restrict__ dst,
                                                     const float* __restrict__ alpha_p,
                                                     float* __restrict__ S) {
    int gid  = blockIdx.x * 256 + threadIdx.x;
    int e    = gid >> 5;
    int lane = gid & 31;
    if (e >= NEDGES) return;
    const float coef = (1.0f - alpha_p[0]) * ew[e];
    const int s = src[e];
    const int d = dst[e];
    const float4 xs = *(const float4*)(x + (long)s * NF + lane * 4);
    float* outp = S + (long)d * NF + lane * 4;
    unsafeAtomicAdd(outp + 0, coef * xs.x);
    unsafeAtomicAdd(outp + 1, coef * xs.y);
    unsafeAtomicAdd(outp + 2, coef * xs.z);
    unsafeAtomicAdd(outp + 3, coef * xs.w);
}

// ========================= epilogue GEMM ====================================
// out = theta*(S@W) + (1-theta)*S + x, in place over S (=d_out). Row-local.
__global__ __launch_bounds__(256) void gemm_out(float* __restrict__ S,
                                                const float* __restrict__ W,
                                                const float* __restrict__ x,
                                                const float* __restrict__ lamda_p,
                                                const int* __restrict__ l_p) {
    __shared__ float Wl[NF * NF];   // 64 KB
    __shared__ float sT[NF * 32];   // 16 KB

    const int tid = threadIdx.x;
    const int rbase = blockIdx.x * 32;

    {
        const float4* Wv = (const float4*)W;
        float4* Wlv = (float4*)Wl;
        #pragma unroll
        for (int i = 0; i < 16; i++)
            Wlv[tid + i * 256] = Wv[tid + i * 256];
    }
    {
        int rl = tid >> 3;
        int c0 = (tid & 7) * 16;
        int row = rbase + rl;
        #pragma unroll
        for (int cc = 0; cc < 16; cc += 4) {
            int c = c0 + cc;
            float4 v = (row < NNODES) ? *(const float4*)(S + (long)row * NF + c)
                                      : make_float4(0.f, 0.f, 0.f, 0.f);
            sT[(c + 0) * 32 + rl] = v.x;
            sT[(c + 1) * 32 + rl] = v.y;
            sT[(c + 2) * 32 + rl] = v.z;
            sT[(c + 3) * 32 + rl] = v.w;
        }
    }
    __syncthreads();

    const int cg   = tid & 31;
    const int slot = tid >> 5;
    const int j0   = cg * 4;
    const int rl0  = slot * 4;

    float acc[4][4];
    #pragma unroll
    for (int r = 0; r < 4; r++)
        #pragma unroll
        for (int c = 0; c < 4; c++) acc[r][c] = 0.f;

    #pragma unroll 4
    for (int k = 0; k < NF; k++) {
        float4 w = *(const float4*)&Wl[k * NF + j0];
        float4 s = *(const float4*)&sT[k * 32 + rl0];
        acc[0][0] += s.x * w.x; acc[0][1] += s.x * w.y; acc[0][2] += s.x * w.z; acc[0][3] += s.x * w.w;
        acc[1][0] += s.y * w.x; acc[1][1] += s.y * w.y; acc[1][2] += s.y * w.z; acc[1][3] += s.y * w.w;
        acc[2][0] += s.z * w.x; acc[2][1] += s.z * w.y; acc[2][2] += s.z * w.z; acc[2][3] += s.z * w.w;
        acc[3][0] += s.w * w.x; acc[3][1] += s.w * w.y; acc[3][2] += s.w * w.z; acc[3][3] += s.w * w.w;
    }

    const float theta = logf(lamda_p[0] / (float)l_p[0] + 1.0f);
    const float omt   = 1.0f - theta;

    #pragma unroll
    for (int r = 0; r < 4; r++) {
        int row = rbase + rl0 + r;
        if (row < NNODES) {
            float4 xv = *(const float4*)(x + (long)row * NF + j0);
            float4 o;
            o.x = theta * acc[r][0] + omt * sT[(j0 + 0) * 32 + rl0 + r] + xv.x;
            o.y = theta * acc[r][1] + omt * sT[(j0 + 1) * 32 + rl0 + r] + xv.y;
            o.z = theta * acc[r][2] + omt * sT[(j0 + 2) * 32 + rl0 + r] + xv.z;
            o.w = theta * acc[r][3] + omt * sT[(j0 + 3) * 32 + rl0 + r] + xv.w;
            *(float4*)(S + (long)row * NF + j0) = o;
        }
    }
}

// ===========================================================================
extern "C" void kernel_launch(void* const* d_in, const int* in_sizes, int n_in,
                              void* d_out, int out_size, void* d_ws, size_t ws_size,
                              hipStream_t stream) {
    const float* x       = (const float*)d_in[0];
    const float* h0      = (const float*)d_in[1];
    const float* edge_w  = (const float*)d_in[2];
    const float* weight  = (const float*)d_in[3];
    const float* lamda   = (const float*)d_in[4];
    const float* alpha   = (const float*)d_in[5];
    const int*   src     = (const int*)d_in[6];
    const int*   dst     = (const int*)d_in[7];
    const int*   l       = (const int*)d_in[8];
    float* out = (float*)d_out;

    const size_t need = (size_t)(NNODES + (NNODES + 1) + NNODES + NEDGES + NEDGES) * 4;
    if (ws_size >= need) {
        int*   deg     = (int*)d_ws;
        int*   offs    = deg + NNODES;
        int*   cursor  = offs + NNODES + 1;
        int*   csr_src = cursor + NNODES;
        float* csr_w   = (float*)(csr_src + NEDGES);

        // bsum/boff scratch lives in d_out (fully overwritten by pull later)
        int* bsum = (int*)d_out;
        int* boff = bsum + 256;

        hipMemsetAsync(deg, 0, NNODES * sizeof(int), stream);
        hist_kernel<<<(NEDGES + 255) / 256, 256, 0, stream>>>(dst, deg);
        scan1_kernel<<<SCAN_BLOCKS, 256, 0, stream>>>(deg, bsum);
        scan2_kernel<<<1, 256, 0, stream>>>(bsum, boff);
        scan3_kernel<<<SCAN_BLOCKS, 256, 0, stream>>>(deg, boff, offs, cursor);
        fill_kernel<<<(NEDGES + 255) / 256, 256, 0, stream>>>(src, dst, edge_w, alpha,
                                                              cursor, csr_src, csr_w);
        pull_kernel<<<(NNODES + 3) / 4, 256, 0, stream>>>(x, h0, alpha, offs,
                                                          csr_src, csr_w, out);
    } else {
        init_support<<<(NNODES * NF / 4 + 255) / 256, 256, 0, stream>>>(h0, alpha, out);
        scatter_edges<<<(NEDGES * 32 + 255) / 256, 256, 0, stream>>>(x, edge_w, src, dst,
                                                                     alpha, out);
    }
    gemm_out<<<(NNODES + 31) / 32, 256, 0, stream>>>(out, weight, x, lamda, l);
}